// Round 12
// baseline (435.400 us; speedup 1.0000x reference)
//
#include <hip/hip_runtime.h>
#include <hip/hip_bf16.h>
#include <hip/hip_fp16.h>
#include <type_traits>

// ---------------------------------------------------------------------------
// GCN: out = relu(Agg(x@W1)+b1) -> relu(Agg(.@W2)+b2) -> .@Wc+bc
// Agg(h)[i] = dinv[i]^2*h[i] + sum_{e: dst=i} dinv[i]*dinv[src]*h[src]
// R1-R8: see history.
// R9 (FAILED): feature-sliced layout + XCD pinning -> 4x line amp. Reverted.
// R10: split-K LDS (occupancy) -> NEUTRAL; gemm was concurrency-bound.
// R11: gemm_pf batch-issue pipeline -> total 395us (best). agg 65.5us,
//     FETCH 195MB. agg FROZEN.
// R12 (FAILED, reverted): nontemporal agg / K-chunked gemm / split CSR.
// R13-R15: 128-node buckets neutral (399us); reverted to 512 buckets.
// R16 (DIAGNOSTIC): agg 4-way split -> top-5 = harness 400MB poison fills
//     (59.8us each, NOT ours). Split cost +31.9us for +6 dispatches =>
//     ~5.3us PER LAUNCH -> R11's 11 dispatches carry ~55-60us launch
//     overhead = the blind-zone mass.
// R17: minimize dispatch count: (a) agg back to 2 full-range launches;
//     (b) k_wcast_all fused into k_histA (disjoint block ranges);
//     (c) scan1+scan3f fused into k_scan_all (redundant-prefix trick).
//     11 -> 9 dispatches.
// R18: R17 RESUBMITTED VERBATIM. R17 bench died with "container failed
//     twice" (same opaque infra error as R8, which passed on identical
//     resubmission). Full audit of the two new kernels found no OOB /
//     unbounded path; all else is R16-passed code. Measure before mutating.
// ---------------------------------------------------------------------------

typedef _Float16 half8 __attribute__((ext_vector_type(8)));
typedef float floatx4 __attribute__((ext_vector_type(4)));

#define EPB 8192    // edges per block in histA/scatterA
#define NBKT 512    // coarse buckets (dst>>8), 256 nodes each
#define BCAP 4608   // bucket capacity: mean 4096, sigma~64 -> +8 sigma
#define WCTOT (32768 + 16384 + 6144)   // fused wcast elements (55296)

// ------------------------- scan helper -------------------------------------

__device__ inline int block_incl_scan_256(int t, int* tmp) {
    int tid = threadIdx.x;
    tmp[tid] = t;
    __syncthreads();
    #pragma unroll
    for (int off = 1; off < 256; off <<= 1) {
        int v = (tid >= off) ? tmp[tid - off] : 0;
        __syncthreads();
        tmp[tid] += v;
        __syncthreads();
    }
    return tmp[tid];
}

// Single-launch full scan (replaces scan1 + scan3f): block b first sums all
// histM elements before its chunk (coalesced, L2-hot, <=393KB for the last
// block), then scans its own chunk. Redundant-prefix trick: one dispatch,
// no bsum round-trip.
template <int ITEMS>
__global__ __launch_bounds__(256) void k_scan_all(const int* __restrict__ vin,
                                                  int* __restrict__ rp, int n) {
    __shared__ int tmp[256];
    int tid = threadIdx.x;
    const int chunk0 = blockIdx.x * (256 * ITEMS);

    int pre = 0;
    for (int i = tid; i < chunk0; i += 256) pre += vin[i];
    block_incl_scan_256(pre, tmp);
    int base0 = tmp[255];
    __syncthreads();   // protect tmp before reuse

    int base = chunk0 + tid * ITEMS;
    int v[ITEMS];
    int t = 0;
    #pragma unroll
    for (int l = 0; l < ITEMS; ++l) {
        int i = base + l;
        v[l] = (i < n) ? vin[i] : 0;
        t += v[l];
    }
    int incl = block_incl_scan_256(t, tmp);
    int run = base0 + incl - t;
    #pragma unroll
    for (int l = 0; l < ITEMS; ++l) {
        int i = base + l;
        if (i < n) rp[i] = run;
        run += v[l];
    }
}

// ----------------------- bucket-sort CSR build -----------------------------

// Fused: blocks [0, nblk) do the coarse histogram; blocks [nblk, nblk+216)
// do the (independent) weight casts W -> Wt fp16 transposed.
__global__ __launch_bounds__(256) void k_histA_wcast(const int* __restrict__ dst,
                                                     int* __restrict__ histM,
                                                     int E, int nblk,
                                                     const float* __restrict__ W1,
                                                     _Float16* __restrict__ W1t,
                                                     const float* __restrict__ W2,
                                                     _Float16* __restrict__ W2t,
                                                     const float* __restrict__ Wc,
                                                     _Float16* __restrict__ Wct) {
    int tid = threadIdx.x;
    if ((int)blockIdx.x >= nblk) {
        int i = ((int)blockIdx.x - nblk) * 256 + tid;
        if (i < 32768) {
            int c = i >> 8, k = i & 255;
            W1t[i] = (_Float16)W1[(size_t)k * 128 + c];
        } else if (i < 32768 + 16384) {
            int j = i - 32768;
            int c = j >> 7, k = j & 127;
            W2t[j] = (_Float16)W2[(size_t)k * 128 + c];
        } else if (i < WCTOT) {
            int j = i - 32768 - 16384;
            int c = j >> 7, k = j & 127;
            Wct[j] = (c < 40) ? (_Float16)Wc[(size_t)k * 40 + c] : (_Float16)0.f;
        }
        return;
    }
    __shared__ int h[NBKT];
    for (int i = tid; i < NBKT; i += 256) h[i] = 0;
    __syncthreads();
    int base = blockIdx.x * EPB;
    #pragma unroll 4
    for (int l = 0; l < EPB / 256; ++l) {
        int i = base + l * 256 + tid;
        if (i < E) atomicAdd(&h[dst[i] >> 8], 1);
    }
    __syncthreads();
    for (int i = tid; i < NBKT; i += 256)
        histM[i * nblk + blockIdx.x] = h[i];
}

// scatter edges into bucket-grouped u64 array; each (block,bucket) run is
// contiguous (~16 edges = two 64B lines), no global atomics.
__global__ __launch_bounds__(256) void k_scatterA(const int* __restrict__ src,
                                                  const int* __restrict__ dst,
                                                  const int* __restrict__ histS,
                                                  unsigned long long* __restrict__ eB,
                                                  int E, int nblk) {
    __shared__ int bse[NBKT];
    __shared__ int cnt[NBKT];
    int tid = threadIdx.x;
    for (int i = tid; i < NBKT; i += 256) {
        bse[i] = histS[i * nblk + blockIdx.x];
        cnt[i] = 0;
    }
    __syncthreads();
    int base = blockIdx.x * EPB;
    #pragma unroll 4
    for (int l = 0; l < EPB / 256; ++l) {
        int i = base + l * 256 + tid;
        if (i < E) {
            int d = dst[i];
            int s = src[i];
            int b = d >> 8;
            int r = atomicAdd(&cnt[b], 1);
            eB[bse[b] + r] = ((unsigned long long)(unsigned)d << 32) | (unsigned)s;
        }
    }
}

// one block per bucket (256 nodes): LDS counting sort by dst&255; emits
// srcS coalesced; rowptr/deg/dinv via LDS bsearch on sorted digits.
__global__ __launch_bounds__(256) void k_sortB(const unsigned long long* __restrict__ eB,
                                               const int* __restrict__ histS,
                                               int* __restrict__ srcS,
                                               int* __restrict__ rowptr,
                                               float* __restrict__ dinv,
                                               int n, int E, int nblk) {
    const int b   = blockIdx.x;
    const int tid = threadIdx.x;
    const int ni0 = b << 8;
    int s0 = histS[b * nblk];
    int s1 = (b < NBKT - 1) ? histS[(b + 1) * nblk] : E;
    int cnt = s1 - s0;
    if (cnt > BCAP) cnt = BCAP;          // statistically unreachable (+8 sigma)
    if (cnt == 0 && ni0 > n) return;

    __shared__ int hist[256];
    __shared__ int tmp[256];
    __shared__ int baseA[256];
    __shared__ int cntA[256];
    __shared__ short dstL[BCAP];
    __shared__ unsigned srcL[BCAP];
    __shared__ int lbA[256];

    hist[tid] = 0;
    cntA[tid] = 0;
    __syncthreads();
    for (int i = s0 + tid; i < s0 + cnt; i += 256)
        atomicAdd(&hist[(int)(eB[i] >> 32) & 255], 1);
    __syncthreads();
    int own  = hist[tid];
    int incl = block_incl_scan_256(own, tmp);
    baseA[tid] = incl - own;
    __syncthreads();
    for (int i = s0 + tid; i < s0 + cnt; i += 256) {
        unsigned long long v = eB[i];
        int dig = (int)(v >> 32) & 255;
        int r = atomicAdd(&cntA[dig], 1);
        int pos = baseA[dig] + r;
        dstL[pos] = (short)dig;
        srcL[pos] = (unsigned)v;
    }
    __syncthreads();
    // coalesced src emit
    for (int j = tid; j < cnt; j += 256)
        srcS[s0 + j] = (int)srcL[j];
    // rowptr / dinv for nodes [ni0, ni0+256) (and rowptr[n] if it falls here)
    if (ni0 <= n) {
        int lo = 0, hi = cnt;
        while (lo < hi) {
            int mid = (lo + hi) >> 1;
            if ((int)dstL[mid] < tid) lo = mid + 1; else hi = mid;
        }
        lbA[tid] = lo;
        __syncthreads();
        int i = ni0 + tid;
        if (i <= n) {
            rowptr[i] = s0 + lo;
            if (i < n) {
                int ub = (tid < 255) ? lbA[tid + 1] : cnt;
                dinv[i] = rsqrtf((float)(ub - lo + 1));
            }
        }
    }
}

// ----------------------- MFMA GEMM (batch-issue pipeline, R11) -------------
// C[M,N] = A[M,K] @ W[K,N] via v_mfma_f32_16x16x32_f16.
// Per lane: ALL A loads for its row segment issued first (single base +
// imm offsets), then Wt staged to LDS (single shot), ONE barrier, then
// pure cvt+MFMA loop. 16KB/wave VMEM in flight. Wave = 16 rows x BN cols.

template <int K, int BN, typename AT, typename OT>
__global__ __launch_bounds__(256) void gemm_pf(const AT* __restrict__ A,
                                               const _Float16* __restrict__ Wt,
                                               const float* __restrict__ bias,
                                               OT* __restrict__ C,
                                               int M, int N) {
    constexpr int KP = K + 8;
    constexpr int NT = BN / 16;
    constexpr int KS = K / 32;
    __shared__ __align__(16) _Float16 Bs[BN * KP];

    const int tid  = threadIdx.x;
    const int lane = tid & 63;
    const int wv   = tid >> 6;
    const int qd   = lane >> 4;
    const int ln15 = lane & 15;
    const int bm   = blockIdx.x * 64;

    int row  = bm + wv * 16 + ln15;
    int rowc = (row < M) ? row : (M - 1);   // clamp: loads safe, stores guarded

    // (1) issue ALL A loads back-to-back (independent, one base each)
    float4 af[std::is_same<AT, float>::value ? KS : 1][2];
    half8  ah[std::is_same<AT, float>::value ? 1 : KS];
    if constexpr (std::is_same<AT, float>::value) {
        const float* p = A + (size_t)rowc * K + qd * 8;
        #pragma unroll
        for (int ks = 0; ks < KS; ++ks) {
            af[ks][0] = *(const float4*)(p + ks * 32);
            af[ks][1] = *(const float4*)(p + ks * 32 + 4);
        }
    } else {
        const _Float16* p = (const _Float16*)A + (size_t)rowc * K + qd * 8;
        #pragma unroll
        for (int ks = 0; ks < KS; ++ks)
            ah[ks] = *(const half8*)(p + ks * 32);
    }

    // (2) stage all of Wt into LDS
    constexpr int TOT = BN * K / 8;
    #pragma unroll
    for (int i = 0; i < TOT / 256; ++i) {
        int idx = (i * 256 + tid) * 8;
        int col = idx / K;
        int kk  = idx % K;
        *(uint4*)&Bs[col * KP + kk] = *(const uint4*)(Wt + idx);
    }
    __syncthreads();

    // (3) pure MFMA loop
    floatx4 acc[NT];
    #pragma unroll
    for (int c = 0; c < NT; ++c) acc[c] = (floatx4){0.f, 0.f, 0.f, 0.f};

    #pragma unroll
    for (int ks = 0; ks < KS; ++ks) {
        half8 a;
        if constexpr (std::is_same<AT, float>::value) {
            float4 v0 = af[ks][0];
            float4 v1 = af[ks][1];
            a[0] = (_Float16)v0.x; a[1] = (_Float16)v0.y;
            a[2] = (_Float16)v0.z; a[3] = (_Float16)v0.w;
            a[4] = (_Float16)v1.x; a[5] = (_Float16)v1.y;
            a[6] = (_Float16)v1.z; a[7] = (_Float16)v1.w;
        } else {
            a = ah[ks];
        }
        #pragma unroll
        for (int c = 0; c < NT; ++c) {
            half8 b = *(const half8*)&Bs[(c * 16 + ln15) * KP + ks * 32 + qd * 8];
            acc[c] = __builtin_amdgcn_mfma_f32_16x16x32_f16(a, b, acc[c], 0, 0, 0);
        }
    }

    // (4) epilogue
    int baseRow = bm + wv * 16 + qd * 4;
    #pragma unroll
    for (int c = 0; c < NT; ++c) {
        int col = c * 16 + ln15;
        if constexpr (std::is_same<OT, _Float16>::value) {
            #pragma unroll
            for (int r = 0; r < 4; ++r) {
                int rr = baseRow + r;
                if (rr < M) C[(size_t)rr * N + col] = (_Float16)acc[c][r];
            }
        } else {
            float bv = (col < N && bias) ? bias[col] : 0.f;
            #pragma unroll
            for (int r = 0; r < 4; ++r) {
                int rr = baseRow + r;
                if (rr < M && col < N)
                    ((float*)C)[(size_t)rr * N + col] = acc[c][r] + bv;
            }
        }
    }
}

// ---------------------------- aggregation (R11, FROZEN) --------------------
// One wave per node; 4 groups x 16 lanes; group owns one edge per step,
// lane loads dwordx4 (8 fp16 cols); ds_bpermute broadcast; cross-group
// shfl_xor(16,32) reduce. Pattern ceiling ~65us / FETCH 195MB (5 confirms).
// R15 defensive index clamp retained (free).

static __device__ __forceinline__ float2 h2f2u(unsigned int raw) {
    __half2 h = *(__half2*)&raw;
    return __half22float2(h);
}

__global__ __launch_bounds__(256) void gcn_agg(const unsigned int* __restrict__ h,
                                               const int* __restrict__ rowptr,
                                               const int* __restrict__ srcS,
                                               const float* __restrict__ dinv,
                                               const float* __restrict__ bias,
                                               unsigned int* __restrict__ out,
                                               int n, int do_relu) {
    int node = blockIdx.x * 4 + (threadIdx.x >> 6);
    if (node >= n) return;
    const int lane = threadIdx.x & 63;
    const int g    = lane >> 4;      // edge group 0..3
    const int t    = lane & 15;      // col chunk: cols [t*8, t*8+8)

    const _Float16* hb = (const _Float16*)h;

    float di = dinv[node];
    int e0 = rowptr[node];
    int e1 = rowptr[node + 1];

    half8 sv = *(const half8*)(hb + (size_t)(unsigned)node * 128 + t * 8);
    const float4* b4 = (const float4*)bias;
    float4 blo = b4[t * 2 + 0];
    float4 bhi = b4[t * 2 + 1];

    float2 acc[4];
    #pragma unroll
    for (int i = 0; i < 4; ++i) acc[i] = make_float2(0.f, 0.f);

    const unsigned nclamp = (unsigned)n - 1u;
    for (int ce = e0; ce < e1; ce += 64) {
        int cnt = e1 - ce;
        cnt = (cnt < 64) ? cnt : 64;
        int colv = 0, wval = 0;
        if (lane < cnt) {
            unsigned c = (unsigned)srcS[ce + lane];
            c = (c < nclamp) ? c : nclamp;   // defensive clamp
            colv = (int)c;
            wval = __float_as_int(di * dinv[c]);
        }
        #pragma unroll 2
        for (int d = 0; d < cnt; d += 4) {
            int idx = (d + g) << 2;
            int c   = __builtin_amdgcn_ds_bpermute(idx, colv);
            float w = __int_as_float(__builtin_amdgcn_ds_bpermute(idx, wval));
            const unsigned* hp = (const unsigned*)(hb + (size_t)(unsigned)c * 128 + t * 8);
            uint4 hv = *(const uint4*)hp;
            float2 u0 = h2f2u(hv.x);
            float2 u1 = h2f2u(hv.y);
            float2 u2 = h2f2u(hv.z);
            float2 u3 = h2f2u(hv.w);
            acc[0].x += u0.x * w; acc[0].y += u0.y * w;
            acc[1].x += u1.x * w; acc[1].y += u1.y * w;
            acc[2].x += u2.x * w; acc[2].y += u2.y * w;
            acc[3].x += u3.x * w; acc[3].y += u3.y * w;
        }
    }

    #pragma unroll
    for (int i = 0; i < 4; ++i) {
        acc[i].x += __shfl_xor(acc[i].x, 16);
        acc[i].y += __shfl_xor(acc[i].y, 16);
        acc[i].x += __shfl_xor(acc[i].x, 32);
        acc[i].y += __shfl_xor(acc[i].y, 32);
    }

    float s = di * di;
    float bb[8] = {blo.x, blo.y, blo.z, blo.w, bhi.x, bhi.y, bhi.z, bhi.w};
    half8 o;
    #pragma unroll
    for (int i = 0; i < 8; ++i) {
        float v = ((i & 1) ? acc[i >> 1].y : acc[i >> 1].x) + (float)sv[i] * s + bb[i];
        if (do_relu) v = fmaxf(v, 0.f);
        o[i] = (_Float16)v;
    }
    if (g == 0)
        *(half8*)((_Float16*)out + (size_t)(unsigned)node * 128 + t * 8) = o;
}

// ------------------------------- launch ------------------------------------

extern "C" void kernel_launch(void* const* d_in, const int* in_sizes, int n_in,
                              void* d_out, int out_size, void* d_ws, size_t ws_size,
                              hipStream_t stream) {
    const float* x  = (const float*)d_in[0];
    const int* eidx = (const int*)d_in[1];
    const float* W1 = (const float*)d_in[2];
    const float* b1 = (const float*)d_in[3];
    const float* W2 = (const float*)d_in[4];
    const float* b2 = (const float*)d_in[5];
    const float* Wc = (const float*)d_in[6];
    const float* bc = (const float*)d_in[7];
    float* out = (float*)d_out;

    const int NF = 256, NH = 128, NC = 40;
    const int n = in_sizes[0] / NF;    // 100000
    const int E = in_sizes[1] / 2;     // 1600000
    const int* src = eidx;
    const int* dst = eidx + E;

    const int nblk = (E + EPB - 1) / EPB;          // 196
    const int hm   = NBKT * nblk;                  // 100352
    const int nbA  = (hm + 4095) / 4096;           // 25

    char* wsb = (char*)d_ws;
    size_t off = 0;
    auto alloc = [&](size_t bytes) {
        char* p = wsb + off;
        off = (off + bytes + 511) & ~(size_t)511;
        return p;
    };
    _Float16* hbuf = (_Float16*)alloc((size_t)n * NH * 2);  // 25.6 MB
    _Float16* abuf = (_Float16*)alloc((size_t)n * NH * 2);  // 25.6 MB
    _Float16* W1t  = (_Float16*)alloc((size_t)128 * 256 * 2);
    _Float16* W2t  = (_Float16*)alloc((size_t)128 * 128 * 2);
    _Float16* Wct  = (_Float16*)alloc((size_t)48 * 128 * 2);
    unsigned long long* eB = (unsigned long long*)alloc((size_t)E * 8);  // 12.8 MB
    int* srcS      = (int*)alloc((size_t)E * 4);            // 6.4 MB
    int* histM     = (int*)alloc((size_t)hm * 4);
    int* histS     = (int*)alloc((size_t)hm * 4);
    int* rowptr    = (int*)alloc((size_t)(n + 1) * 4);
    float* dinv    = (float*)alloc((size_t)n * 4);

    // ---- CSR build + weight cast: 4 dispatches ----
    const int wcBlocks = WCTOT / 256;              // 216
    k_histA_wcast<<<nblk + wcBlocks, 256, 0, stream>>>(dst, histM, E, nblk,
                                                       W1, W1t, W2, W2t, Wc, Wct);
    k_scan_all<16><<<nbA, 256, 0, stream>>>(histM, histS, hm);
    k_scatterA<<<nblk, 256, 0, stream>>>(src, dst, histS, eB, E, nblk);
    k_sortB<<<NBKT, 256, 0, stream>>>(eB, histS, srcS, rowptr, dinv, n, E, nblk);

    // ---- layers: 5 dispatches ----
    const int gB = (n + 63) / 64;   // 1563 blocks, 64 rows each
    gemm_pf<256, 128, float, _Float16><<<gB, 256, 0, stream>>>(x, W1t, nullptr, hbuf, n, NH);
    gcn_agg<<<(n + 3) / 4, 256, 0, stream>>>((const unsigned int*)hbuf, rowptr, srcS, dinv, b1,
                                             (unsigned int*)abuf, n, 1);
    gemm_pf<128, 128, _Float16, _Float16><<<gB, 256, 0, stream>>>(abuf, W2t, nullptr, hbuf, n, NH);
    gcn_agg<<<(n + 3) / 4, 256, 0, stream>>>((const unsigned int*)hbuf, rowptr, srcS, dinv, b2,
                                             (unsigned int*)abuf, n, 1);
    gemm_pf<128, 48, _Float16, float><<<gB, 256, 0, stream>>>(abuf, Wct, bc, out, n, NC);
}

// Round 13
// 390.767 us; speedup vs baseline: 1.1142x; 1.1142x over previous
//
#include <hip/hip_runtime.h>
#include <hip/hip_bf16.h>
#include <hip/hip_fp16.h>
#include <type_traits>

// ---------------------------------------------------------------------------
// GCN: out = relu(Agg(x@W1)+b1) -> relu(Agg(.@W2)+b2) -> .@Wc+bc
// Agg(h)[i] = dinv[i]^2*h[i] + sum_{e: dst=i} dinv[i]*dinv[src]*h[src]
// R1-R8: see history.
// R9 (FAILED): feature-sliced layout + XCD pinning -> 4x line amp. Reverted.
// R10: split-K LDS (occupancy) -> NEUTRAL; gemm was concurrency-bound.
// R11: gemm_pf batch-issue pipeline -> total 395us (BEST). agg 65.5us,
//     FETCH 195MB. agg FROZEN.
// R12 (FAILED, reverted): nontemporal agg / K-chunked gemm / split CSR.
// R13-R15: 128-node buckets neutral (399us); reverted to 512 buckets.
// R16 (DIAGNOSTIC): agg 4-way split -> +32us for +6 dispatches => ~5.3us
//     per launch. Top-5 = harness 400MB poison fills (~59.8us, not ours).
// R17/R18: launch fusion. KEY CALIBRATION: agg dispatch time is constant
//     65.5-65.8us across ALL rounds -> containers equally fast -> total
//     deltas are real. R18 = 435us: k_scan_all's redundant-prefix loop is
//     a ~30us latency-serial kernel (25 blocks = no TLP; 384 dependent
//     strided loads x ~200cyc L2 latency). Fusion lesson: never trade a
//     5us launch for a serial low-occupancy loop.
// R19: k_scan_all -> scan1 + scan3f (proven pair; scan3f prefixes a
//     25-element bsum, trivial). Keep histA+wcast fusion (no serial trap).
//     10 dispatches.
// ---------------------------------------------------------------------------

typedef _Float16 half8 __attribute__((ext_vector_type(8)));
typedef float floatx4 __attribute__((ext_vector_type(4)));

#define EPB 8192    // edges per block in histA/scatterA
#define NBKT 512    // coarse buckets (dst>>8), 256 nodes each
#define BCAP 4608   // bucket capacity: mean 4096, sigma~64 -> +8 sigma
#define WCTOT (32768 + 16384 + 6144)   // fused wcast elements (55296)

// ------------------------- scan helpers ------------------------------------

__device__ inline int block_incl_scan_256(int t, int* tmp) {
    int tid = threadIdx.x;
    tmp[tid] = t;
    __syncthreads();
    #pragma unroll
    for (int off = 1; off < 256; off <<= 1) {
        int v = (tid >= off) ? tmp[tid - off] : 0;
        __syncthreads();
        tmp[tid] += v;
        __syncthreads();
    }
    return tmp[tid];
}

template <int ITEMS>
__global__ __launch_bounds__(256) void k_scan1(const int* __restrict__ v,
                                               int* __restrict__ bsum, int n) {
    __shared__ int tmp[256];
    int base = blockIdx.x * (256 * ITEMS) + threadIdx.x * ITEMS;
    int t = 0;
    #pragma unroll
    for (int l = 0; l < ITEMS; ++l) {
        int i = base + l;
        t += (i < n) ? v[i] : 0;
    }
    block_incl_scan_256(t, tmp);
    if (threadIdx.x == 0) bsum[blockIdx.x] = tmp[255];
}

// scan3 with inlined block-sum prefix: bsum[] holds per-block TOTALS from
// scan1 (25 elements); each block derives its global base via one in-LDS
// scan of that tiny array, then scans its own chunk.
template <int ITEMS>
__global__ __launch_bounds__(256) void k_scan3f(const int* __restrict__ vin,
                                                const int* __restrict__ bsum,
                                                int* __restrict__ rp, int n, int nb) {
    __shared__ int tmp[256];
    int tid = threadIdx.x;
    int bs = (tid < nb && tid < (int)blockIdx.x) ? bsum[tid] : 0;
    block_incl_scan_256(bs, tmp);
    int base0 = tmp[255];
    __syncthreads();   // protect tmp before reuse

    int base = blockIdx.x * (256 * ITEMS) + tid * ITEMS;
    int v[ITEMS];
    int t = 0;
    #pragma unroll
    for (int l = 0; l < ITEMS; ++l) {
        int i = base + l;
        v[l] = (i < n) ? vin[i] : 0;
        t += v[l];
    }
    int incl = block_incl_scan_256(t, tmp);
    int run = base0 + incl - t;
    #pragma unroll
    for (int l = 0; l < ITEMS; ++l) {
        int i = base + l;
        if (i < n) rp[i] = run;
        run += v[l];
    }
}

// ----------------------- bucket-sort CSR build -----------------------------

// Fused: blocks [0, nblk) do the coarse histogram; blocks [nblk, nblk+216)
// do the (independent) weight casts W -> Wt fp16 transposed.
__global__ __launch_bounds__(256) void k_histA_wcast(const int* __restrict__ dst,
                                                     int* __restrict__ histM,
                                                     int E, int nblk,
                                                     const float* __restrict__ W1,
                                                     _Float16* __restrict__ W1t,
                                                     const float* __restrict__ W2,
                                                     _Float16* __restrict__ W2t,
                                                     const float* __restrict__ Wc,
                                                     _Float16* __restrict__ Wct) {
    int tid = threadIdx.x;
    if ((int)blockIdx.x >= nblk) {
        int i = ((int)blockIdx.x - nblk) * 256 + tid;
        if (i < 32768) {
            int c = i >> 8, k = i & 255;
            W1t[i] = (_Float16)W1[(size_t)k * 128 + c];
        } else if (i < 32768 + 16384) {
            int j = i - 32768;
            int c = j >> 7, k = j & 127;
            W2t[j] = (_Float16)W2[(size_t)k * 128 + c];
        } else if (i < WCTOT) {
            int j = i - 32768 - 16384;
            int c = j >> 7, k = j & 127;
            Wct[j] = (c < 40) ? (_Float16)Wc[(size_t)k * 40 + c] : (_Float16)0.f;
        }
        return;
    }
    __shared__ int h[NBKT];
    for (int i = tid; i < NBKT; i += 256) h[i] = 0;
    __syncthreads();
    int base = blockIdx.x * EPB;
    #pragma unroll 4
    for (int l = 0; l < EPB / 256; ++l) {
        int i = base + l * 256 + tid;
        if (i < E) atomicAdd(&h[dst[i] >> 8], 1);
    }
    __syncthreads();
    for (int i = tid; i < NBKT; i += 256)
        histM[i * nblk + blockIdx.x] = h[i];
}

// scatter edges into bucket-grouped u64 array; each (block,bucket) run is
// contiguous (~16 edges = two 64B lines), no global atomics.
__global__ __launch_bounds__(256) void k_scatterA(const int* __restrict__ src,
                                                  const int* __restrict__ dst,
                                                  const int* __restrict__ histS,
                                                  unsigned long long* __restrict__ eB,
                                                  int E, int nblk) {
    __shared__ int bse[NBKT];
    __shared__ int cnt[NBKT];
    int tid = threadIdx.x;
    for (int i = tid; i < NBKT; i += 256) {
        bse[i] = histS[i * nblk + blockIdx.x];
        cnt[i] = 0;
    }
    __syncthreads();
    int base = blockIdx.x * EPB;
    #pragma unroll 4
    for (int l = 0; l < EPB / 256; ++l) {
        int i = base + l * 256 + tid;
        if (i < E) {
            int d = dst[i];
            int s = src[i];
            int b = d >> 8;
            int r = atomicAdd(&cnt[b], 1);
            eB[bse[b] + r] = ((unsigned long long)(unsigned)d << 32) | (unsigned)s;
        }
    }
}

// one block per bucket (256 nodes): LDS counting sort by dst&255; emits
// srcS coalesced; rowptr/deg/dinv via LDS bsearch on sorted digits.
__global__ __launch_bounds__(256) void k_sortB(const unsigned long long* __restrict__ eB,
                                               const int* __restrict__ histS,
                                               int* __restrict__ srcS,
                                               int* __restrict__ rowptr,
                                               float* __restrict__ dinv,
                                               int n, int E, int nblk) {
    const int b   = blockIdx.x;
    const int tid = threadIdx.x;
    const int ni0 = b << 8;
    int s0 = histS[b * nblk];
    int s1 = (b < NBKT - 1) ? histS[(b + 1) * nblk] : E;
    int cnt = s1 - s0;
    if (cnt > BCAP) cnt = BCAP;          // statistically unreachable (+8 sigma)
    if (cnt == 0 && ni0 > n) return;

    __shared__ int hist[256];
    __shared__ int tmp[256];
    __shared__ int baseA[256];
    __shared__ int cntA[256];
    __shared__ short dstL[BCAP];
    __shared__ unsigned srcL[BCAP];
    __shared__ int lbA[256];

    hist[tid] = 0;
    cntA[tid] = 0;
    __syncthreads();
    for (int i = s0 + tid; i < s0 + cnt; i += 256)
        atomicAdd(&hist[(int)(eB[i] >> 32) & 255], 1);
    __syncthreads();
    int own  = hist[tid];
    int incl = block_incl_scan_256(own, tmp);
    baseA[tid] = incl - own;
    __syncthreads();
    for (int i = s0 + tid; i < s0 + cnt; i += 256) {
        unsigned long long v = eB[i];
        int dig = (int)(v >> 32) & 255;
        int r = atomicAdd(&cntA[dig], 1);
        int pos = baseA[dig] + r;
        dstL[pos] = (short)dig;
        srcL[pos] = (unsigned)v;
    }
    __syncthreads();
    // coalesced src emit
    for (int j = tid; j < cnt; j += 256)
        srcS[s0 + j] = (int)srcL[j];
    // rowptr / dinv for nodes [ni0, ni0+256) (and rowptr[n] if it falls here)
    if (ni0 <= n) {
        int lo = 0, hi = cnt;
        while (lo < hi) {
            int mid = (lo + hi) >> 1;
            if ((int)dstL[mid] < tid) lo = mid + 1; else hi = mid;
        }
        lbA[tid] = lo;
        __syncthreads();
        int i = ni0 + tid;
        if (i <= n) {
            rowptr[i] = s0 + lo;
            if (i < n) {
                int ub = (tid < 255) ? lbA[tid + 1] : cnt;
                dinv[i] = rsqrtf((float)(ub - lo + 1));
            }
        }
    }
}

// ----------------------- MFMA GEMM (batch-issue pipeline, R11) -------------
// C[M,N] = A[M,K] @ W[K,N] via v_mfma_f32_16x16x32_f16.
// Per lane: ALL A loads for its row segment issued first (single base +
// imm offsets), then Wt staged to LDS (single shot), ONE barrier, then
// pure cvt+MFMA loop. 16KB/wave VMEM in flight. Wave = 16 rows x BN cols.

template <int K, int BN, typename AT, typename OT>
__global__ __launch_bounds__(256) void gemm_pf(const AT* __restrict__ A,
                                               const _Float16* __restrict__ Wt,
                                               const float* __restrict__ bias,
                                               OT* __restrict__ C,
                                               int M, int N) {
    constexpr int KP = K + 8;
    constexpr int NT = BN / 16;
    constexpr int KS = K / 32;
    __shared__ __align__(16) _Float16 Bs[BN * KP];

    const int tid  = threadIdx.x;
    const int lane = tid & 63;
    const int wv   = tid >> 6;
    const int qd   = lane >> 4;
    const int ln15 = lane & 15;
    const int bm   = blockIdx.x * 64;

    int row  = bm + wv * 16 + ln15;
    int rowc = (row < M) ? row : (M - 1);   // clamp: loads safe, stores guarded

    // (1) issue ALL A loads back-to-back (independent, one base each)
    float4 af[std::is_same<AT, float>::value ? KS : 1][2];
    half8  ah[std::is_same<AT, float>::value ? 1 : KS];
    if constexpr (std::is_same<AT, float>::value) {
        const float* p = A + (size_t)rowc * K + qd * 8;
        #pragma unroll
        for (int ks = 0; ks < KS; ++ks) {
            af[ks][0] = *(const float4*)(p + ks * 32);
            af[ks][1] = *(const float4*)(p + ks * 32 + 4);
        }
    } else {
        const _Float16* p = (const _Float16*)A + (size_t)rowc * K + qd * 8;
        #pragma unroll
        for (int ks = 0; ks < KS; ++ks)
            ah[ks] = *(const half8*)(p + ks * 32);
    }

    // (2) stage all of Wt into LDS
    constexpr int TOT = BN * K / 8;
    #pragma unroll
    for (int i = 0; i < TOT / 256; ++i) {
        int idx = (i * 256 + tid) * 8;
        int col = idx / K;
        int kk  = idx % K;
        *(uint4*)&Bs[col * KP + kk] = *(const uint4*)(Wt + idx);
    }
    __syncthreads();

    // (3) pure MFMA loop
    floatx4 acc[NT];
    #pragma unroll
    for (int c = 0; c < NT; ++c) acc[c] = (floatx4){0.f, 0.f, 0.f, 0.f};

    #pragma unroll
    for (int ks = 0; ks < KS; ++ks) {
        half8 a;
        if constexpr (std::is_same<AT, float>::value) {
            float4 v0 = af[ks][0];
            float4 v1 = af[ks][1];
            a[0] = (_Float16)v0.x; a[1] = (_Float16)v0.y;
            a[2] = (_Float16)v0.z; a[3] = (_Float16)v0.w;
            a[4] = (_Float16)v1.x; a[5] = (_Float16)v1.y;
            a[6] = (_Float16)v1.z; a[7] = (_Float16)v1.w;
        } else {
            a = ah[ks];
        }
        #pragma unroll
        for (int c = 0; c < NT; ++c) {
            half8 b = *(const half8*)&Bs[(c * 16 + ln15) * KP + ks * 32 + qd * 8];
            acc[c] = __builtin_amdgcn_mfma_f32_16x16x32_f16(a, b, acc[c], 0, 0, 0);
        }
    }

    // (4) epilogue
    int baseRow = bm + wv * 16 + qd * 4;
    #pragma unroll
    for (int c = 0; c < NT; ++c) {
        int col = c * 16 + ln15;
        if constexpr (std::is_same<OT, _Float16>::value) {
            #pragma unroll
            for (int r = 0; r < 4; ++r) {
                int rr = baseRow + r;
                if (rr < M) C[(size_t)rr * N + col] = (_Float16)acc[c][r];
            }
        } else {
            float bv = (col < N && bias) ? bias[col] : 0.f;
            #pragma unroll
            for (int r = 0; r < 4; ++r) {
                int rr = baseRow + r;
                if (rr < M && col < N)
                    ((float*)C)[(size_t)rr * N + col] = acc[c][r] + bv;
            }
        }
    }
}

// ---------------------------- aggregation (R11, FROZEN) --------------------
// One wave per node; 4 groups x 16 lanes; group owns one edge per step,
// lane loads dwordx4 (8 fp16 cols); ds_bpermute broadcast; cross-group
// shfl_xor(16,32) reduce. Pattern ceiling ~65.5-65.8us / FETCH 195MB
// (6 confirmations; also the cross-round container calibration).
// R15 defensive index clamp retained (free).

static __device__ __forceinline__ float2 h2f2u(unsigned int raw) {
    __half2 h = *(__half2*)&raw;
    return __half22float2(h);
}

__global__ __launch_bounds__(256) void gcn_agg(const unsigned int* __restrict__ h,
                                               const int* __restrict__ rowptr,
                                               const int* __restrict__ srcS,
                                               const float* __restrict__ dinv,
                                               const float* __restrict__ bias,
                                               unsigned int* __restrict__ out,
                                               int n, int do_relu) {
    int node = blockIdx.x * 4 + (threadIdx.x >> 6);
    if (node >= n) return;
    const int lane = threadIdx.x & 63;
    const int g    = lane >> 4;      // edge group 0..3
    const int t    = lane & 15;      // col chunk: cols [t*8, t*8+8)

    const _Float16* hb = (const _Float16*)h;

    float di = dinv[node];
    int e0 = rowptr[node];
    int e1 = rowptr[node + 1];

    half8 sv = *(const half8*)(hb + (size_t)(unsigned)node * 128 + t * 8);
    const float4* b4 = (const float4*)bias;
    float4 blo = b4[t * 2 + 0];
    float4 bhi = b4[t * 2 + 1];

    float2 acc[4];
    #pragma unroll
    for (int i = 0; i < 4; ++i) acc[i] = make_float2(0.f, 0.f);

    const unsigned nclamp = (unsigned)n - 1u;
    for (int ce = e0; ce < e1; ce += 64) {
        int cnt = e1 - ce;
        cnt = (cnt < 64) ? cnt : 64;
        int colv = 0, wval = 0;
        if (lane < cnt) {
            unsigned c = (unsigned)srcS[ce + lane];
            c = (c < nclamp) ? c : nclamp;   // defensive clamp
            colv = (int)c;
            wval = __float_as_int(di * dinv[c]);
        }
        #pragma unroll 2
        for (int d = 0; d < cnt; d += 4) {
            int idx = (d + g) << 2;
            int c   = __builtin_amdgcn_ds_bpermute(idx, colv);
            float w = __int_as_float(__builtin_amdgcn_ds_bpermute(idx, wval));
            const unsigned* hp = (const unsigned*)(hb + (size_t)(unsigned)c * 128 + t * 8);
            uint4 hv = *(const uint4*)hp;
            float2 u0 = h2f2u(hv.x);
            float2 u1 = h2f2u(hv.y);
            float2 u2 = h2f2u(hv.z);
            float2 u3 = h2f2u(hv.w);
            acc[0].x += u0.x * w; acc[0].y += u0.y * w;
            acc[1].x += u1.x * w; acc[1].y += u1.y * w;
            acc[2].x += u2.x * w; acc[2].y += u2.y * w;
            acc[3].x += u3.x * w; acc[3].y += u3.y * w;
        }
    }

    #pragma unroll
    for (int i = 0; i < 4; ++i) {
        acc[i].x += __shfl_xor(acc[i].x, 16);
        acc[i].y += __shfl_xor(acc[i].y, 16);
        acc[i].x += __shfl_xor(acc[i].x, 32);
        acc[i].y += __shfl_xor(acc[i].y, 32);
    }

    float s = di * di;
    float bb[8] = {blo.x, blo.y, blo.z, blo.w, bhi.x, bhi.y, bhi.z, bhi.w};
    half8 o;
    #pragma unroll
    for (int i = 0; i < 8; ++i) {
        float v = ((i & 1) ? acc[i >> 1].y : acc[i >> 1].x) + (float)sv[i] * s + bb[i];
        if (do_relu) v = fmaxf(v, 0.f);
        o[i] = (_Float16)v;
    }
    if (g == 0)
        *(half8*)((_Float16*)out + (size_t)(unsigned)node * 128 + t * 8) = o;
}

// ------------------------------- launch ------------------------------------

extern "C" void kernel_launch(void* const* d_in, const int* in_sizes, int n_in,
                              void* d_out, int out_size, void* d_ws, size_t ws_size,
                              hipStream_t stream) {
    const float* x  = (const float*)d_in[0];
    const int* eidx = (const int*)d_in[1];
    const float* W1 = (const float*)d_in[2];
    const float* b1 = (const float*)d_in[3];
    const float* W2 = (const float*)d_in[4];
    const float* b2 = (const float*)d_in[5];
    const float* Wc = (const float*)d_in[6];
    const float* bc = (const float*)d_in[7];
    float* out = (float*)d_out;

    const int NF = 256, NH = 128, NC = 40;
    const int n = in_sizes[0] / NF;    // 100000
    const int E = in_sizes[1] / 2;     // 1600000
    const int* src = eidx;
    const int* dst = eidx + E;

    const int nblk = (E + EPB - 1) / EPB;          // 196
    const int hm   = NBKT * nblk;                  // 100352
    const int nbA  = (hm + 4095) / 4096;           // 25

    char* wsb = (char*)d_ws;
    size_t off = 0;
    auto alloc = [&](size_t bytes) {
        char* p = wsb + off;
        off = (off + bytes + 511) & ~(size_t)511;
        return p;
    };
    _Float16* hbuf = (_Float16*)alloc((size_t)n * NH * 2);  // 25.6 MB
    _Float16* abuf = (_Float16*)alloc((size_t)n * NH * 2);  // 25.6 MB
    _Float16* W1t  = (_Float16*)alloc((size_t)128 * 256 * 2);
    _Float16* W2t  = (_Float16*)alloc((size_t)128 * 128 * 2);
    _Float16* Wct  = (_Float16*)alloc((size_t)48 * 128 * 2);
    unsigned long long* eB = (unsigned long long*)alloc((size_t)E * 8);  // 12.8 MB
    int* srcS      = (int*)alloc((size_t)E * 4);            // 6.4 MB
    int* histM     = (int*)alloc((size_t)hm * 4);
    int* histS     = (int*)alloc((size_t)hm * 4);
    int* rowptr    = (int*)alloc((size_t)(n + 1) * 4);
    float* dinv    = (float*)alloc((size_t)n * 4);
    int* bsumA     = (int*)alloc(1024);

    // ---- CSR build + weight cast: 5 dispatches ----
    const int wcBlocks = WCTOT / 256;              // 216
    k_histA_wcast<<<nblk + wcBlocks, 256, 0, stream>>>(dst, histM, E, nblk,
                                                       W1, W1t, W2, W2t, Wc, Wct);
    k_scan1<16><<<nbA, 256, 0, stream>>>(histM, bsumA, hm);
    k_scan3f<16><<<nbA, 256, 0, stream>>>(histM, bsumA, histS, hm, nbA);
    k_scatterA<<<nblk, 256, 0, stream>>>(src, dst, histS, eB, E, nblk);
    k_sortB<<<NBKT, 256, 0, stream>>>(eB, histS, srcS, rowptr, dinv, n, E, nblk);

    // ---- layers: 5 dispatches ----
    const int gB = (n + 63) / 64;   // 1563 blocks, 64 rows each
    gemm_pf<256, 128, float, _Float16><<<gB, 256, 0, stream>>>(x, W1t, nullptr, hbuf, n, NH);
    gcn_agg<<<(n + 3) / 4, 256, 0, stream>>>((const unsigned int*)hbuf, rowptr, srcS, dinv, b1,
                                             (unsigned int*)abuf, n, 1);
    gemm_pf<128, 128, _Float16, _Float16><<<gB, 256, 0, stream>>>(abuf, W2t, nullptr, hbuf, n, NH);
    gcn_agg<<<(n + 3) / 4, 256, 0, stream>>>((const unsigned int*)hbuf, rowptr, srcS, dinv, b2,
                                             (unsigned int*)abuf, n, 1);
    gemm_pf<128, 48, _Float16, float><<<gB, 256, 0, stream>>>(abuf, Wct, bc, out, n, NC);
}